// Round 10
// baseline (602.513 us; speedup 1.0000x reference)
//
#include <hip/hip_runtime.h>

typedef unsigned short u16;
typedef unsigned int u32;
typedef __attribute__((ext_vector_type(8))) short short8;   // 8 bf16 (MFMA A/B frag)
typedef __attribute__((ext_vector_type(4))) float f32x4;    // MFMA C/D frag
typedef __attribute__((ext_vector_type(4))) float fvec4;
typedef __attribute__((ext_vector_type(4))) u16 u16x4;

__device__ __forceinline__ u16 f2bf(float f) {
  u32 u = __float_as_uint(f);
  u += 0x7FFFu + ((u >> 16) & 1u);   // RTNE
  return (u16)(u >> 16);
}

// wave-local LDS fence: drains this wave's ds ops only (lgkmcnt), does NOT touch vmcnt
// so global prefetches stay in flight. sched_barrier pins ordering.
__device__ __forceinline__ void wave_lds_fence() {
  asm volatile("s_waitcnt lgkmcnt(0)" ::: "memory");
  __builtin_amdgcn_sched_barrier(0);
}

// memory row index of token (Bg,h,w); rows of x are 256 elems.
__device__ __forceinline__ int m_of(int Bg, int h, int w) {
  return ((Bg >> 2) << 14) | ((h & 3) << 12) | ((((Bg & 3) << 1) | (h >> 5)) << 9) |
         (((h >> 2) & 7) << 6) | w;
}

__device__ __forceinline__ f32x4 mfma16(short8 a, short8 b, f32x4 c) {
  return __builtin_amdgcn_mfma_f32_16x16x32_bf16(a, b, c, 0, 0, 0);
}

// qkvB blocked layout: element (channel c, token m) lives at (c>>2)*262144 + m*4 + (c&3).
// ld8: 8 consecutive channels (c4*4 .. c4*4+7) at token m -> short8 via two 8B loads.
__device__ __forceinline__ short8 ld8(const u16* __restrict__ qb, int c4, int m) {
  union { u16x4 h[2]; short8 v; } u;
  u.h[0] = *(const u16x4*)(qb + (size_t)c4 * 262144 + (size_t)m * 4);
  u.h[1] = *(const u16x4*)(qb + (size_t)(c4 + 1) * 262144 + (size_t)m * 4);
  return u.v;
}

// ---------------- prep: convert W to bf16, materialize bias matrices ----------------
__global__ void k_prep(const float* __restrict__ qkv_w, const float* __restrict__ t0,
                       const float* __restrict__ t1, u16* __restrict__ wb,
                       float* __restrict__ bias4, float* __restrict__ bias8) {
  int tid = blockIdx.x * 256 + threadIdx.x;
  int stride = gridDim.x * 256;
  for (int i = tid; i < 768 * 256; i += stride) wb[i] = f2bf(qkv_w[i]);
  for (int i = tid; i < 4 * 64 * 64; i += stride) {
    int g = i >> 12, n = (i >> 6) & 63, m = i & 63;
    int di = (n >> 3) - (m >> 3) + 7, dj = (n & 7) - (m & 7) + 7;
    bias8[i] = t1[(di * 15 + dj) * 4 + g];
  }
  for (int i = tid; i < 4 * 16 * 16; i += stride) {
    int g = i >> 8, n = (i >> 4) & 15, m = i & 15;
    int di = (n >> 2) - (m >> 2) + 3, dj = (n & 3) - (m & 3) + 3;
    bias4[i] = t0[(di * 7 + dj) * 4 + g];
  }
}

// ---------------- QKV GEMM: [65536 x 256] x [256 x 768] -> qkvB blocked layout ------------
// Grid 2048: bid>>10 = col-half (384 cols), bid&1023 = 64-row m-tile. 8 waves; wave owns
// 48 cols x 64 rows. LDS = 40960B EXACT (As 64x128 K-half 16KB + Bs 24KB) -> 4 blocks/CU
// = 32 waves/CU. A staged in TWO K-halves (restage mid-kernel, 2 barriers, amortized by
// 4-block TLP). K-loop: read chunk -> write next chunk (DS in-order => WAR safe) ->
// prefetch chunk+2 -> MFMAs. VGPR pinned <=64 by __launch_bounds__(512,8).
__global__ __launch_bounds__(512, 8) void k_gemm(const float* __restrict__ x,
                                                 const u16* __restrict__ wb,
                                                 const float* __restrict__ qkv_b,
                                                 u16* __restrict__ qkvB) {
  __shared__ __align__(16) u16 As[64 * 128];      // 16384 B, XOR slot-swizzled, K-half
  __shared__ __align__(16) u16 Bs[384 * 32];      // 24576 B, per-wave 48-col slabs
  const int t = threadIdx.x;
  const int wid = t >> 6, l = t & 63;
  const int lr = l & 15, lk4 = l >> 4;
  const int mt = blockIdx.x & 1023, nh = blockIdx.x >> 10;
  const size_t xbase = (size_t)mt * 64 * 256;
  const int colbase = nh * 384;            // this block's first output col

  // wave owns local cols wid*48 .. wid*48+47
  int goff[3], loff[3];
#pragma unroll
  for (int j = 0; j < 3; ++j) {
    int u = wid * 192 + j * 64 + l;        // unit = 8 u16 of one (col,slot)
    int cu = u >> 2, su = u & 3;
    goff[j] = (colbase + cu) * 256 + su * 8;                 // global (u16 units)
    loff[j] = cu * 32 + ((su ^ ((cu >> 1) & 3)) * 8);        // swizzled LDS addr
  }
  // A-stage unit mapping: 4 units/thread, unit = row x 8B-halfslot
  const int sr0 = t >> 5;                  // rows sr0, sr0+16, ... (u>>5 for j incr 512)
  const int scc = (t & 31) * 4;            // u16 col within 128-half
  const int sslot = scc >> 3, shalf = scc & 7;

  // ---- prologue: chunk0 B loads, stage A half0, write Bs chunk0, prefetch chunk1 ----
  short8 bstg0[3], bstg[3];
#pragma unroll
  for (int j = 0; j < 3; ++j) bstg0[j] = *(const short8*)(wb + goff[j]);
  {
    const float* xp = x + xbase + (size_t)sr0 * 256 + scc;
#pragma unroll
    for (int j = 0; j < 4; ++j) {
      fvec4 v = *(const fvec4*)(xp + j * 16 * 256);
      int r = sr0 + j * 16;
      u16x4 u;
      u[0] = f2bf(v[0]); u[1] = f2bf(v[1]); u[2] = f2bf(v[2]); u[3] = f2bf(v[3]);
      *(u16x4*)&As[r * 128 + ((sslot ^ (r & 7)) << 3) + shalf] = u;
    }
  }
#pragma unroll
  for (int j = 0; j < 3; ++j) *(short8*)&Bs[loff[j]] = bstg0[j];
#pragma unroll
  for (int j = 0; j < 3; ++j) bstg[j] = *(const short8*)(wb + goff[j] + 32);

  f32x4 acc[3][4];
  const f32x4 z = {0.f, 0.f, 0.f, 0.f};
#pragma unroll
  for (int jt = 0; jt < 3; ++jt)
#pragma unroll
    for (int rt = 0; rt < 4; ++rt) acc[jt][rt] = z;

  __syncthreads();  // As half0 + Bs chunk0 visible

  const int bswz = (lr >> 1) & 3;          // B-read slot swizzle
#pragma unroll
  for (int khalf = 0; khalf < 2; ++khalf) {
    if (khalf == 1) {
      __syncthreads();                     // all waves done reading As half0
      const float* xp = x + xbase + (size_t)sr0 * 256 + 128 + scc;
#pragma unroll
      for (int j = 0; j < 4; ++j) {
        fvec4 v = *(const fvec4*)(xp + j * 16 * 256);
        int r = sr0 + j * 16;
        u16x4 u;
        u[0] = f2bf(v[0]); u[1] = f2bf(v[1]); u[2] = f2bf(v[2]); u[3] = f2bf(v[3]);
        *(u16x4*)&As[r * 128 + ((sslot ^ (r & 7)) << 3) + shalf] = u;
      }
      __syncthreads();                     // As half1 visible
    }
#pragma unroll
    for (int i = 0; i < 4; ++i) {
      const int ci = khalf * 4 + i;        // global chunk index 0..7
      const int kk = i * 32;               // K offset within this half
      // reads of chunk ci; DS in-order per wave => safe to overwrite the slab after
      short8 a[4], b[3];
#pragma unroll
      for (int rt = 0; rt < 4; ++rt) {
        int row = rt * 16 + lr;
        a[rt] = *(const short8*)&As[row * 128 + ((((kk >> 3) + lk4) ^ (row & 7)) << 3)];
      }
#pragma unroll
      for (int jt = 0; jt < 3; ++jt)
        b[jt] = *(const short8*)&Bs[(wid * 48 + jt * 16 + lr) * 32 + ((lk4 ^ bswz) * 8)];
      __builtin_amdgcn_sched_barrier(0);   // keep the writes below AFTER the reads above
      // write chunk ci+1 (regs prefetched one iter ago; vmcnt wait ~free)
      if (ci < 7) {
#pragma unroll
        for (int j = 0; j < 3; ++j) *(short8*)&Bs[loff[j]] = bstg[j];
      }
      // prefetch chunk ci+2; stays in flight under the MFMAs
      if (ci < 6) {
#pragma unroll
        for (int j = 0; j < 3; ++j)
          bstg[j] = *(const short8*)(wb + goff[j] + (ci + 2) * 32);
      }
#pragma unroll
      for (int jt = 0; jt < 3; ++jt)
#pragma unroll
        for (int rt = 0; rt < 4; ++rt)
          acc[jt][rt] = mfma16(b[jt], a[rt], acc[jt][rt]);  // reg-dim = col
    }
  }

  // ---- epilogue: + bias, blocked layout -> per-lane u16x4, coalesced ----
  const int rows0 = mt * 64;
#pragma unroll
  for (int jt = 0; jt < 3; ++jt) {
    int col0 = colbase + wid * 48 + jt * 16 + lk4 * 4;
    fvec4 bb = *(const fvec4*)(qkv_b + col0);
    int c40 = col0 >> 2;
#pragma unroll
    for (int rt = 0; rt < 4; ++rt) {
      int row = rows0 + rt * 16 + lr;
      u16x4 u;
#pragma unroll
      for (int r = 0; r < 4; ++r) u[r] = f2bf(acc[jt][rt][r] + bb[r]);
      *(u16x4*)&qkvB[(size_t)c40 * 262144 + (size_t)row * 4] = u;
    }
  }
}

// ---------------- attention ws=8 (group 1, channels 128..255) ----------------
// block = 1 window (1024 blocks), wave = head; all LDS buffers per-wave -> no barriers
__global__ __launch_bounds__(256) void k_attn8(const u16* __restrict__ qkvB,
                                               const float* __restrict__ bias8,
                                               float* __restrict__ out) {
  __shared__ __align__(16) u16 vt[4 * 32 * 72];  // per-wave V^T [e][m] (pad 8)
  __shared__ __align__(16) u16 pl[4 * 64 * 72];  // per-wave P [n][m]; reused as O f32 [64][33]
  int bid = blockIdx.x;
  int Bg = bid >> 6, wi = (bid >> 3) & 7, wj = bid & 7;
  int h0 = wi * 8, w0 = wj * 8;
  int g = threadIdx.x >> 6, l = threadIdx.x & 63;
  int lr = l & 15, lk4 = l >> 4;
  u16* vtg = vt + g * (32 * 72);
  u16* plg = pl + g * (64 * 72);

  // load Q,K fragments straight from global (A-layout: row=l&15, k-chunk=(l>>4)*8)
  const int c4q = 32 + g * 8 + lk4 * 2;   // q chans 128+g*32+lk4*8
  const int c4k = 96 + g * 8 + lk4 * 2;   // k chans 384+g*32+lk4*8
  short8 aq[4], bk[4];
#pragma unroll
  for (int tn = 0; tn < 4; ++tn) {
    int n = tn * 16 + lr;
    int m = m_of(Bg, h0 + (n >> 3), w0 + (n & 7));
    aq[tn] = ld8(qkvB, c4q, m);
    bk[tn] = ld8(qkvB, c4k, m);
  }
  // stage V^T: lane l owns token m=l; v chans 640+g*32 .. +31 (8 c4-groups)
  {
    int m = m_of(Bg, h0 + (l >> 3), w0 + (l & 7));
#pragma unroll
    for (int j2 = 0; j2 < 8; ++j2) {
      u16x4 p = *(const u16x4*)(qkvB + (size_t)(160 + g * 8 + j2) * 262144 + (size_t)m * 4);
#pragma unroll
      for (int r = 0; r < 4; ++r) vtg[(j2 * 4 + r) * 72 + l] = p[r];
    }
  }
  // S = q k^T  (16 MFMAs)
  f32x4 z = {0.f, 0.f, 0.f, 0.f};
  f32x4 s[4][4];
#pragma unroll
  for (int tn = 0; tn < 4; ++tn)
#pragma unroll
    for (int tm = 0; tm < 4; ++tm) s[tn][tm] = mfma16(aq[tn], bk[tm], z);

  const float scale = 0.17677669529663687f;  // 1/sqrt(32)
#pragma unroll
  for (int tn = 0; tn < 4; ++tn)
#pragma unroll
    for (int tm = 0; tm < 4; ++tm)
#pragma unroll
      for (int r = 0; r < 4; ++r) {
        int n = tn * 16 + lk4 * 4 + r, m = tm * 16 + lr;
        s[tn][tm][r] = s[tn][tm][r] * scale + bias8[(g * 64 + n) * 64 + m];
      }
  // softmax over m (row n lives in 16 lanes sharing l>>4)
  float invden[4][4];
#pragma unroll
  for (int tn = 0; tn < 4; ++tn)
#pragma unroll
    for (int r = 0; r < 4; ++r) {
      float mx = fmaxf(fmaxf(s[tn][0][r], s[tn][1][r]), fmaxf(s[tn][2][r], s[tn][3][r]));
#pragma unroll
      for (int d = 1; d < 16; d <<= 1) mx = fmaxf(mx, __shfl_xor(mx, d));
      float sum = 0.f;
#pragma unroll
      for (int tm = 0; tm < 4; ++tm) {
        float p = __expf(s[tn][tm][r] - mx);
        s[tn][tm][r] = p;
        sum += p;
      }
#pragma unroll
      for (int d = 1; d < 16; d <<= 1) sum += __shfl_xor(sum, d);
      invden[tn][r] = 1.f / sum;
    }
  // P -> LDS (bf16)
#pragma unroll
  for (int tn = 0; tn < 4; ++tn)
#pragma unroll
    for (int tm = 0; tm < 4; ++tm)
#pragma unroll
      for (int r = 0; r < 4; ++r)
        plg[(tn * 16 + lk4 * 4 + r) * 72 + tm * 16 + lr] = f2bf(s[tn][tm][r]);
  wave_lds_fence();
  // O = P V  (16 MFMAs)
  f32x4 o[4][2];
#pragma unroll
  for (int tn = 0; tn < 4; ++tn) { o[tn][0] = z; o[tn][1] = z; }
#pragma unroll
  for (int kc = 0; kc < 2; ++kc) {
    short8 pa[4], vb[2];
#pragma unroll
    for (int tn = 0; tn < 4; ++tn)
      pa[tn] = *(const short8*)&plg[(tn * 16 + lr) * 72 + kc * 32 + lk4 * 8];
#pragma unroll
    for (int te = 0; te < 2; ++te)
      vb[te] = *(const short8*)&vtg[(te * 16 + lr) * 72 + kc * 32 + lk4 * 8];
#pragma unroll
    for (int tn = 0; tn < 4; ++tn)
#pragma unroll
      for (int te = 0; te < 2; ++te) o[tn][te] = mfma16(pa[tn], vb[te], o[tn][te]);
  }
  wave_lds_fence();
  // scale by 1/denom, transpose O through LDS (overlay on plg)
  float* ol = (float*)plg;  // [64][33]
#pragma unroll
  for (int tn = 0; tn < 4; ++tn)
#pragma unroll
    for (int te = 0; te < 2; ++te)
#pragma unroll
      for (int r = 0; r < 4; ++r) {
        int n = tn * 16 + lk4 * 4 + r;
        ol[n * 33 + te * 16 + lr] = o[tn][te][r] * invden[tn][r];
      }
  wave_lds_fence();
  // store: lane = token, loop e -> 32B-chunk coalesced runs along w
  {
    int h = h0 + (l >> 3), w = w0 + (l & 7);
    size_t base = ((size_t)(Bg >> 2)) * 4194304 + (size_t)(((Bg & 3) * 2 + (h >> 5))) * 131072 +
                  (size_t)(((h >> 2) & 7)) * 16384 + (size_t)((h & 3) * 64 + w);
#pragma unroll
    for (int e = 0; e < 32; ++e) {
      int c = 128 + g * 32 + e;
      size_t idx = base + (size_t)(c >> 6) * 1048576 + (size_t)((c >> 3) & 7) * 2048 +
                   (size_t)(c & 7) * 256;
      out[idx] = ol[l * 33 + e];
    }
  }
}

// ---------------- attention ws=4 (group 0, channels 0..127) ----------------
// block = 4 windows (1024 blocks), wave = window, heads looped; per-wave buffers -> no barriers
__global__ __launch_bounds__(256) void k_attn4(const u16* __restrict__ qkvB,
                                               const float* __restrict__ bias4,
                                               float* __restrict__ out) {
  __shared__ __align__(16) u16 vt[4 * 32 * 40];   // per-wave V^T [e][m0..32] (m 16..31 zero)
  __shared__ __align__(16) u16 pl[4 * 16 * 40];   // per-wave P [n][m0..32] (m 16..31 zero)
  __shared__ __align__(16) float ol[4 * 16 * 33]; // per-wave O
  int wv = threadIdx.x >> 6, l = threadIdx.x & 63;
  int wid = blockIdx.x * 4 + wv;
  int Bg = wid >> 8, wi = (wid >> 4) & 15, wj = wid & 15;
  int h0 = wi * 4, w0 = wj * 4;
  int lr = l & 15, lk4 = l >> 4;
  u16* vtw = vt + wv * (32 * 40);
  u16* plw = pl + wv * (16 * 40);
  float* olw = ol + wv * (16 * 33);
  f32x4 z = {0.f, 0.f, 0.f, 0.f};
  short8 z8 = {0, 0, 0, 0, 0, 0, 0, 0};
  const float scale = 0.17677669529663687f;

  // per-lane token index
  int hq = h0 + (lr >> 2), wq = w0 + (lr & 3);
  const int mq = m_of(Bg, hq, wq);

  for (int g = 0; g < 4; ++g) {
    short8 aq = ld8(qkvB, g * 8 + lk4 * 2, mq);          // q chans g*32+lk4*8
    short8 bk = ld8(qkvB, 64 + g * 8 + lk4 * 2, mq);     // k chans 256+g*32+lk4*8
    // stage V^T: lane = (token lr) x (e-chunk lk4)
    {
      short8 v = ld8(qkvB, 128 + g * 8 + lk4 * 2, mq);   // v chans 512+g*32+lk4*8
#pragma unroll
      for (int j = 0; j < 8; ++j) vtw[(lk4 * 8 + j) * 40 + lr] = (u16)v[j];
      // zero pad m in [16,32)
      *(short8*)&vtw[(l >> 1) * 40 + 16 + (l & 1) * 8] = z8;
    }
    // S (1 MFMA), C rows n = lk4*4+r, cols m = lr
    f32x4 s = mfma16(aq, bk, z);
#pragma unroll
    for (int r = 0; r < 4; ++r) {
      int n = lk4 * 4 + r;
      s[r] = s[r] * scale + bias4[(g * 16 + n) * 16 + lr];
    }
    float invden[4];
#pragma unroll
    for (int r = 0; r < 4; ++r) {
      float mx = s[r];
#pragma unroll
      for (int d = 1; d < 16; d <<= 1) mx = fmaxf(mx, __shfl_xor(mx, d));
      float p = __expf(s[r] - mx);
      s[r] = p;
      float sum = p;
#pragma unroll
      for (int d = 1; d < 16; d <<= 1) sum += __shfl_xor(sum, d);
      invden[r] = 1.f / sum;
    }
    // P -> LDS + zero pad
#pragma unroll
    for (int r = 0; r < 4; ++r) plw[(lk4 * 4 + r) * 40 + lr] = f2bf(s[r]);
    *(u16x4*)&plw[lr * 40 + 16 + lk4 * 4] = (u16x4){0, 0, 0, 0};
    wave_lds_fence();
    // O = P V : 2 MFMAs (te halves), K zero-padded to 32
    f32x4 o[2];
#pragma unroll
    for (int te = 0; te < 2; ++te) {
      short8 pa = *(const short8*)&plw[lr * 40 + lk4 * 8];
      short8 vb = *(const short8*)&vtw[(te * 16 + lr) * 40 + lk4 * 8];
      o[te] = mfma16(pa, vb, z);
    }
#pragma unroll
    for (int te = 0; te < 2; ++te)
#pragma unroll
      for (int r = 0; r < 4; ++r) {
        int n = lk4 * 4 + r;
        olw[n * 33 + te * 16 + lr] = o[te][r] * invden[r];
      }
    wave_lds_fence();
    // store: lane = (token lr) x (e-chunk lk4)
    {
      int h = h0 + (lr >> 2), w = w0 + (lr & 3);
      size_t base = ((size_t)(Bg >> 2)) * 4194304 +
                    (size_t)(((Bg & 3) * 2 + (h >> 5))) * 131072 +
                    (size_t)(((h >> 2) & 7)) * 16384 + (size_t)((h & 3) * 64 + w);
#pragma unroll
      for (int ee = 0; ee < 8; ++ee) {
        int e = lk4 * 8 + ee;
        int c = g * 32 + e;
        size_t idx = base + (size_t)(c >> 6) * 1048576 + (size_t)((c >> 3) & 7) * 2048 +
                     (size_t)(c & 7) * 256;
        out[idx] = olw[lr * 33 + e];
      }
    }
    wave_lds_fence();  // protect per-wave buffer reuse across g iterations
  }
}

extern "C" void kernel_launch(void* const* d_in, const int* in_sizes, int n_in,
                              void* d_out, int out_size, void* d_ws, size_t ws_size,
                              hipStream_t stream) {
  const float* x = (const float*)d_in[0];
  const float* qkv_w = (const float*)d_in[1];
  const float* qkv_b = (const float*)d_in[2];
  const float* t0 = (const float*)d_in[3];
  const float* t1 = (const float*)d_in[4];
  float* out = (float*)d_out;
  char* ws = (char*)d_ws;

  u16* qkvB = (u16*)ws;                         // 192*65536*4 u16  = 100663296 B
  u16* wb = (u16*)(ws + 100663296);             // 768*256*2        = 393216 B
  float* bias8 = (float*)(ws + 101056512);      // 4*64*64*4        = 65536 B
  float* bias4 = (float*)(ws + 101122048);      // 4*16*16*4        = 4096 B

  k_prep<<<256, 256, 0, stream>>>(qkv_w, t0, t1, wb, bias4, bias8);
  k_gemm<<<2048, 512, 0, stream>>>(x, wb, qkv_b, qkvB);
  k_attn8<<<1024, 256, 0, stream>>>(qkvB, bias8, out);
  k_attn4<<<1024, 256, 0, stream>>>(qkvB, bias4, out);
}

// Round 11
// 118.401 us; speedup vs baseline: 5.0888x; 5.0888x over previous
//
#include <hip/hip_runtime.h>

typedef unsigned short u16;
typedef unsigned int u32;
typedef __attribute__((ext_vector_type(8))) short short8;   // 8 bf16 (MFMA A/B frag)
typedef __attribute__((ext_vector_type(4))) float f32x4;    // MFMA C/D frag
typedef __attribute__((ext_vector_type(4))) float fvec4;
typedef __attribute__((ext_vector_type(4))) u16 u16x4;

__device__ __forceinline__ u16 f2bf(float f) {
  u32 u = __float_as_uint(f);
  u += 0x7FFFu + ((u >> 16) & 1u);   // RTNE
  return (u16)(u >> 16);
}

// wave-local LDS fence: drains this wave's ds ops only (lgkmcnt), does NOT touch vmcnt
// so global prefetches stay in flight. sched_barrier pins ordering.
__device__ __forceinline__ void wave_lds_fence() {
  asm volatile("s_waitcnt lgkmcnt(0)" ::: "memory");
  __builtin_amdgcn_sched_barrier(0);
}

// memory row index of token (Bg,h,w); rows of x are 256 elems.
__device__ __forceinline__ int m_of(int Bg, int h, int w) {
  return ((Bg >> 2) << 14) | ((h & 3) << 12) | ((((Bg & 3) << 1) | (h >> 5)) << 9) |
         (((h >> 2) & 7) << 6) | w;
}

__device__ __forceinline__ f32x4 mfma16(short8 a, short8 b, f32x4 c) {
  return __builtin_amdgcn_mfma_f32_16x16x32_bf16(a, b, c, 0, 0, 0);
}

// qkvB blocked layout: element (channel c, token m) lives at (c>>2)*262144 + m*4 + (c&3).
// ld8: 8 consecutive channels (c4*4 .. c4*4+7) at token m -> short8 via two 8B loads.
__device__ __forceinline__ short8 ld8(const u16* __restrict__ qb, int c4, int m) {
  union { u16x4 h[2]; short8 v; } u;
  u.h[0] = *(const u16x4*)(qb + (size_t)c4 * 262144 + (size_t)m * 4);
  u.h[1] = *(const u16x4*)(qb + (size_t)(c4 + 1) * 262144 + (size_t)m * 4);
  return u.v;
}

// ---------------- prep: convert W to bf16, materialize bias matrices ----------------
__global__ void k_prep(const float* __restrict__ qkv_w, const float* __restrict__ t0,
                       const float* __restrict__ t1, u16* __restrict__ wb,
                       float* __restrict__ bias4, float* __restrict__ bias8) {
  int tid = blockIdx.x * 256 + threadIdx.x;
  int stride = gridDim.x * 256;
  for (int i = tid; i < 768 * 256; i += stride) wb[i] = f2bf(qkv_w[i]);
  for (int i = tid; i < 4 * 64 * 64; i += stride) {
    int g = i >> 12, n = (i >> 6) & 63, m = i & 63;
    int di = (n >> 3) - (m >> 3) + 7, dj = (n & 7) - (m & 7) + 7;
    bias8[i] = t1[(di * 15 + dj) * 4 + g];
  }
  for (int i = tid; i < 4 * 16 * 16; i += stride) {
    int g = i >> 8, n = (i >> 4) & 15, m = i & 15;
    int di = (n >> 2) - (m >> 2) + 3, dj = (n & 3) - (m & 3) + 3;
    bias4[i] = t0[(di * 7 + dj) * 4 + g];
  }
}

// ---------------- QKV GEMM: [65536 x 256] x [256 x 768] -> qkvB blocked layout ------------
// Grid 2048: bid>>10 = col-half (384 cols), bid&1023 = 64-row m-tile. 8 waves; wave owns
// 48 cols x 64 rows. LDS = 40960B EXACT (As 64x128 K-half 16KB + Bs 24KB) -> LDS permits
// 4 blocks/CU; natural VGPR ~60 (round 9) permits 8 waves/SIMD -> 32 waves/CU.
// __launch_bounds__(512,4): guaranteed-safe bound (does NOT force spill; r8/r10 lesson).
// A staged in TWO K-halves (restage mid-kernel). K-loop: read chunk -> write next chunk
// (DS in-order => WAR safe) -> prefetch chunk+2 -> MFMAs.
__global__ __launch_bounds__(512, 4) void k_gemm(const float* __restrict__ x,
                                                 const u16* __restrict__ wb,
                                                 const float* __restrict__ qkv_b,
                                                 u16* __restrict__ qkvB) {
  __shared__ __align__(16) u16 As[64 * 128];      // 16384 B, XOR slot-swizzled, K-half
  __shared__ __align__(16) u16 Bs[384 * 32];      // 24576 B, per-wave 48-col slabs
  const int t = threadIdx.x;
  const int wid = t >> 6, l = t & 63;
  const int lr = l & 15, lk4 = l >> 4;
  const int mt = blockIdx.x & 1023, nh = blockIdx.x >> 10;
  const size_t xbase = (size_t)mt * 64 * 256;
  const int colbase = nh * 384;            // this block's first output col

  // wave owns local cols wid*48 .. wid*48+47
  int goff[3], loff[3];
#pragma unroll
  for (int j = 0; j < 3; ++j) {
    int u = wid * 192 + j * 64 + l;        // unit = 8 u16 of one (col,slot)
    int cu = u >> 2, su = u & 3;
    goff[j] = (colbase + cu) * 256 + su * 8;                 // global (u16 units)
    loff[j] = cu * 32 + ((su ^ ((cu >> 1) & 3)) * 8);        // swizzled LDS addr
  }
  // A-stage unit mapping: 4 units/thread, unit = row x 8B-halfslot
  const int sr0 = t >> 5;                  // rows sr0, sr0+16, sr0+32, sr0+48
  const int scc = (t & 31) * 4;            // u16 col within 128-half
  const int sslot = scc >> 3, shalf = scc & 7;

  // ---- prologue: chunk0 B loads, stage A half0, write Bs chunk0, prefetch chunk1 ----
  short8 bstg0[3], bstg[3];
#pragma unroll
  for (int j = 0; j < 3; ++j) bstg0[j] = *(const short8*)(wb + goff[j]);
  {
    const float* xp = x + xbase + (size_t)sr0 * 256 + scc;
#pragma unroll
    for (int j = 0; j < 4; ++j) {
      fvec4 v = *(const fvec4*)(xp + j * 16 * 256);
      int r = sr0 + j * 16;
      u16x4 u;
      u[0] = f2bf(v[0]); u[1] = f2bf(v[1]); u[2] = f2bf(v[2]); u[3] = f2bf(v[3]);
      *(u16x4*)&As[r * 128 + ((sslot ^ (r & 7)) << 3) + shalf] = u;
    }
  }
#pragma unroll
  for (int j = 0; j < 3; ++j) *(short8*)&Bs[loff[j]] = bstg0[j];
#pragma unroll
  for (int j = 0; j < 3; ++j) bstg[j] = *(const short8*)(wb + goff[j] + 32);

  f32x4 acc[3][4];
  const f32x4 z = {0.f, 0.f, 0.f, 0.f};
#pragma unroll
  for (int jt = 0; jt < 3; ++jt)
#pragma unroll
    for (int rt = 0; rt < 4; ++rt) acc[jt][rt] = z;

  __syncthreads();  // As half0 + Bs chunk0 visible

  const int bswz = (lr >> 1) & 3;          // B-read slot swizzle
#pragma unroll
  for (int khalf = 0; khalf < 2; ++khalf) {
    if (khalf == 1) {
      __syncthreads();                     // all waves done reading As half0
      const float* xp = x + xbase + (size_t)sr0 * 256 + 128 + scc;
#pragma unroll
      for (int j = 0; j < 4; ++j) {
        fvec4 v = *(const fvec4*)(xp + j * 16 * 256);
        int r = sr0 + j * 16;
        u16x4 u;
        u[0] = f2bf(v[0]); u[1] = f2bf(v[1]); u[2] = f2bf(v[2]); u[3] = f2bf(v[3]);
        *(u16x4*)&As[r * 128 + ((sslot ^ (r & 7)) << 3) + shalf] = u;
      }
      __syncthreads();                     // As half1 visible
    }
#pragma unroll
    for (int i = 0; i < 4; ++i) {
      const int ci = khalf * 4 + i;        // global chunk index 0..7
      const int kk = i * 32;               // K offset within this half
      // reads of chunk ci; DS in-order per wave => safe to overwrite the slab after
      short8 a[4], b[3];
#pragma unroll
      for (int rt = 0; rt < 4; ++rt) {
        int row = rt * 16 + lr;
        a[rt] = *(const short8*)&As[row * 128 + ((((kk >> 3) + lk4) ^ (row & 7)) << 3)];
      }
#pragma unroll
      for (int jt = 0; jt < 3; ++jt)
        b[jt] = *(const short8*)&Bs[(wid * 48 + jt * 16 + lr) * 32 + ((lk4 ^ bswz) * 8)];
      __builtin_amdgcn_sched_barrier(0);   // keep the writes below AFTER the reads above
      // write chunk ci+1 (regs prefetched one iter ago; vmcnt wait ~free)
      if (ci < 7) {
#pragma unroll
        for (int j = 0; j < 3; ++j) *(short8*)&Bs[loff[j]] = bstg[j];
      }
      // prefetch chunk ci+2; stays in flight under the MFMAs
      if (ci < 6) {
#pragma unroll
        for (int j = 0; j < 3; ++j)
          bstg[j] = *(const short8*)(wb + goff[j] + (ci + 2) * 32);
      }
#pragma unroll
      for (int jt = 0; jt < 3; ++jt)
#pragma unroll
        for (int rt = 0; rt < 4; ++rt)
          acc[jt][rt] = mfma16(b[jt], a[rt], acc[jt][rt]);  // reg-dim = col
    }
  }

  // ---- epilogue: + bias, blocked layout -> per-lane u16x4, coalesced ----
  const int rows0 = mt * 64;
#pragma unroll
  for (int jt = 0; jt < 3; ++jt) {
    int col0 = colbase + wid * 48 + jt * 16 + lk4 * 4;
    fvec4 bb = *(const fvec4*)(qkv_b + col0);
    int c40 = col0 >> 2;
#pragma unroll
    for (int rt = 0; rt < 4; ++rt) {
      int row = rows0 + rt * 16 + lr;
      u16x4 u;
#pragma unroll
      for (int r = 0; r < 4; ++r) u[r] = f2bf(acc[jt][rt][r] + bb[r]);
      *(u16x4*)&qkvB[(size_t)c40 * 262144 + (size_t)row * 4] = u;
    }
  }
}

// ---------------- attention ws=8 (group 1, channels 128..255) ----------------
// block = 1 window (1024 blocks), wave = head; all LDS buffers per-wave -> no barriers
__global__ __launch_bounds__(256) void k_attn8(const u16* __restrict__ qkvB,
                                               const float* __restrict__ bias8,
                                               float* __restrict__ out) {
  __shared__ __align__(16) u16 vt[4 * 32 * 72];  // per-wave V^T [e][m] (pad 8)
  __shared__ __align__(16) u16 pl[4 * 64 * 72];  // per-wave P [n][m]; reused as O f32 [64][33]
  int bid = blockIdx.x;
  int Bg = bid >> 6, wi = (bid >> 3) & 7, wj = bid & 7;
  int h0 = wi * 8, w0 = wj * 8;
  int g = threadIdx.x >> 6, l = threadIdx.x & 63;
  int lr = l & 15, lk4 = l >> 4;
  u16* vtg = vt + g * (32 * 72);
  u16* plg = pl + g * (64 * 72);

  // load Q,K fragments straight from global (A-layout: row=l&15, k-chunk=(l>>4)*8)
  const int c4q = 32 + g * 8 + lk4 * 2;   // q chans 128+g*32+lk4*8
  const int c4k = 96 + g * 8 + lk4 * 2;   // k chans 384+g*32+lk4*8
  short8 aq[4], bk[4];
#pragma unroll
  for (int tn = 0; tn < 4; ++tn) {
    int n = tn * 16 + lr;
    int m = m_of(Bg, h0 + (n >> 3), w0 + (n & 7));
    aq[tn] = ld8(qkvB, c4q, m);
    bk[tn] = ld8(qkvB, c4k, m);
  }
  // stage V^T: lane l owns token m=l; v chans 640+g*32 .. +31 (8 c4-groups)
  {
    int m = m_of(Bg, h0 + (l >> 3), w0 + (l & 7));
#pragma unroll
    for (int j2 = 0; j2 < 8; ++j2) {
      u16x4 p = *(const u16x4*)(qkvB + (size_t)(160 + g * 8 + j2) * 262144 + (size_t)m * 4);
#pragma unroll
      for (int r = 0; r < 4; ++r) vtg[(j2 * 4 + r) * 72 + l] = p[r];
    }
  }
  // S = q k^T  (16 MFMAs)
  f32x4 z = {0.f, 0.f, 0.f, 0.f};
  f32x4 s[4][4];
#pragma unroll
  for (int tn = 0; tn < 4; ++tn)
#pragma unroll
    for (int tm = 0; tm < 4; ++tm) s[tn][tm] = mfma16(aq[tn], bk[tm], z);

  const float scale = 0.17677669529663687f;  // 1/sqrt(32)
#pragma unroll
  for (int tn = 0; tn < 4; ++tn)
#pragma unroll
    for (int tm = 0; tm < 4; ++tm)
#pragma unroll
      for (int r = 0; r < 4; ++r) {
        int n = tn * 16 + lk4 * 4 + r, m = tm * 16 + lr;
        s[tn][tm][r] = s[tn][tm][r] * scale + bias8[(g * 64 + n) * 64 + m];
      }
  // softmax over m (row n lives in 16 lanes sharing l>>4)
  float invden[4][4];
#pragma unroll
  for (int tn = 0; tn < 4; ++tn)
#pragma unroll
    for (int r = 0; r < 4; ++r) {
      float mx = fmaxf(fmaxf(s[tn][0][r], s[tn][1][r]), fmaxf(s[tn][2][r], s[tn][3][r]));
#pragma unroll
      for (int d = 1; d < 16; d <<= 1) mx = fmaxf(mx, __shfl_xor(mx, d));
      float sum = 0.f;
#pragma unroll
      for (int tm = 0; tm < 4; ++tm) {
        float p = __expf(s[tn][tm][r] - mx);
        s[tn][tm][r] = p;
        sum += p;
      }
#pragma unroll
      for (int d = 1; d < 16; d <<= 1) sum += __shfl_xor(sum, d);
      invden[tn][r] = 1.f / sum;
    }
  // P -> LDS (bf16)
#pragma unroll
  for (int tn = 0; tn < 4; ++tn)
#pragma unroll
    for (int tm = 0; tm < 4; ++tm)
#pragma unroll
      for (int r = 0; r < 4; ++r)
        plg[(tn * 16 + lk4 * 4 + r) * 72 + tm * 16 + lr] = f2bf(s[tn][tm][r]);
  wave_lds_fence();
  // O = P V  (16 MFMAs)
  f32x4 o[4][2];
#pragma unroll
  for (int tn = 0; tn < 4; ++tn) { o[tn][0] = z; o[tn][1] = z; }
#pragma unroll
  for (int kc = 0; kc < 2; ++kc) {
    short8 pa[4], vb[2];
#pragma unroll
    for (int tn = 0; tn < 4; ++tn)
      pa[tn] = *(const short8*)&plg[(tn * 16 + lr) * 72 + kc * 32 + lk4 * 8];
#pragma unroll
    for (int te = 0; te < 2; ++te)
      vb[te] = *(const short8*)&vtg[(te * 16 + lr) * 72 + kc * 32 + lk4 * 8];
#pragma unroll
    for (int tn = 0; tn < 4; ++tn)
#pragma unroll
      for (int te = 0; te < 2; ++te) o[tn][te] = mfma16(pa[tn], vb[te], o[tn][te]);
  }
  wave_lds_fence();
  // scale by 1/denom, transpose O through LDS (overlay on plg)
  float* ol = (float*)plg;  // [64][33]
#pragma unroll
  for (int tn = 0; tn < 4; ++tn)
#pragma unroll
    for (int te = 0; te < 2; ++te)
#pragma unroll
      for (int r = 0; r < 4; ++r) {
        int n = tn * 16 + lk4 * 4 + r;
        ol[n * 33 + te * 16 + lr] = o[tn][te][r] * invden[tn][r];
      }
  wave_lds_fence();
  // store: lane = token, loop e -> 32B-chunk coalesced runs along w
  {
    int h = h0 + (l >> 3), w = w0 + (l & 7);
    size_t base = ((size_t)(Bg >> 2)) * 4194304 + (size_t)(((Bg & 3) * 2 + (h >> 5))) * 131072 +
                  (size_t)(((h >> 2) & 7)) * 16384 + (size_t)((h & 3) * 64 + w);
#pragma unroll
    for (int e = 0; e < 32; ++e) {
      int c = 128 + g * 32 + e;
      size_t idx = base + (size_t)(c >> 6) * 1048576 + (size_t)((c >> 3) & 7) * 2048 +
                   (size_t)(c & 7) * 256;
      out[idx] = ol[l * 33 + e];
    }
  }
}

// ---------------- attention ws=4 (group 0, channels 0..127) ----------------
// block = 4 windows (1024 blocks), wave = window, heads looped; per-wave buffers -> no barriers
__global__ __launch_bounds__(256) void k_attn4(const u16* __restrict__ qkvB,
                                               const float* __restrict__ bias4,
                                               float* __restrict__ out) {
  __shared__ __align__(16) u16 vt[4 * 32 * 40];   // per-wave V^T [e][m0..32] (m 16..31 zero)
  __shared__ __align__(16) u16 pl[4 * 16 * 40];   // per-wave P [n][m0..32] (m 16..31 zero)
  __shared__ __align__(16) float ol[4 * 16 * 33]; // per-wave O
  int wv = threadIdx.x >> 6, l = threadIdx.x & 63;
  int wid = blockIdx.x * 4 + wv;
  int Bg = wid >> 8, wi = (wid >> 4) & 15, wj = wid & 15;
  int h0 = wi * 4, w0 = wj * 4;
  int lr = l & 15, lk4 = l >> 4;
  u16* vtw = vt + wv * (32 * 40);
  u16* plw = pl + wv * (16 * 40);
  float* olw = ol + wv * (16 * 33);
  f32x4 z = {0.f, 0.f, 0.f, 0.f};
  short8 z8 = {0, 0, 0, 0, 0, 0, 0, 0};
  const float scale = 0.17677669529663687f;

  // per-lane token index
  int hq = h0 + (lr >> 2), wq = w0 + (lr & 3);
  const int mq = m_of(Bg, hq, wq);

  for (int g = 0; g < 4; ++g) {
    short8 aq = ld8(qkvB, g * 8 + lk4 * 2, mq);          // q chans g*32+lk4*8
    short8 bk = ld8(qkvB, 64 + g * 8 + lk4 * 2, mq);     // k chans 256+g*32+lk4*8
    // stage V^T: lane = (token lr) x (e-chunk lk4)
    {
      short8 v = ld8(qkvB, 128 + g * 8 + lk4 * 2, mq);   // v chans 512+g*32+lk4*8
#pragma unroll
      for (int j = 0; j < 8; ++j) vtw[(lk4 * 8 + j) * 40 + lr] = (u16)v[j];
      // zero pad m in [16,32)
      *(short8*)&vtw[(l >> 1) * 40 + 16 + (l & 1) * 8] = z8;
    }
    // S (1 MFMA), C rows n = lk4*4+r, cols m = lr
    f32x4 s = mfma16(aq, bk, z);
#pragma unroll
    for (int r = 0; r < 4; ++r) {
      int n = lk4 * 4 + r;
      s[r] = s[r] * scale + bias4[(g * 16 + n) * 16 + lr];
    }
    float invden[4];
#pragma unroll
    for (int r = 0; r < 4; ++r) {
      float mx = s[r];
#pragma unroll
      for (int d = 1; d < 16; d <<= 1) mx = fmaxf(mx, __shfl_xor(mx, d));
      float p = __expf(s[r] - mx);
      s[r] = p;
      float sum = p;
#pragma unroll
      for (int d = 1; d < 16; d <<= 1) sum += __shfl_xor(sum, d);
      invden[r] = 1.f / sum;
    }
    // P -> LDS + zero pad
#pragma unroll
    for (int r = 0; r < 4; ++r) plw[(lk4 * 4 + r) * 40 + lr] = f2bf(s[r]);
    *(u16x4*)&plw[lr * 40 + 16 + lk4 * 4] = (u16x4){0, 0, 0, 0};
    wave_lds_fence();
    // O = P V : 2 MFMAs (te halves), K zero-padded to 32
    f32x4 o[2];
#pragma unroll
    for (int te = 0; te < 2; ++te) {
      short8 pa = *(const short8*)&plw[lr * 40 + lk4 * 8];
      short8 vb = *(const short8*)&vtw[(te * 16 + lr) * 40 + lk4 * 8];
      o[te] = mfma16(pa, vb, z);
    }
#pragma unroll
    for (int te = 0; te < 2; ++te)
#pragma unroll
      for (int r = 0; r < 4; ++r) {
        int n = lk4 * 4 + r;
        olw[n * 33 + te * 16 + lr] = o[te][r] * invden[r];
      }
    wave_lds_fence();
    // store: lane = (token lr) x (e-chunk lk4)
    {
      int h = h0 + (lr >> 2), w = w0 + (lr & 3);
      size_t base = ((size_t)(Bg >> 2)) * 4194304 +
                    (size_t)(((Bg & 3) * 2 + (h >> 5))) * 131072 +
                    (size_t)(((h >> 2) & 7)) * 16384 + (size_t)((h & 3) * 64 + w);
#pragma unroll
      for (int ee = 0; ee < 8; ++ee) {
        int e = lk4 * 8 + ee;
        int c = g * 32 + e;
        size_t idx = base + (size_t)(c >> 6) * 1048576 + (size_t)((c >> 3) & 7) * 2048 +
                     (size_t)(c & 7) * 256;
        out[idx] = olw[lr * 33 + e];
      }
    }
    wave_lds_fence();  // protect per-wave buffer reuse across g iterations
  }
}

extern "C" void kernel_launch(void* const* d_in, const int* in_sizes, int n_in,
                              void* d_out, int out_size, void* d_ws, size_t ws_size,
                              hipStream_t stream) {
  const float* x = (const float*)d_in[0];
  const float* qkv_w = (const float*)d_in[1];
  const float* qkv_b = (const float*)d_in[2];
  const float* t0 = (const float*)d_in[3];
  const float* t1 = (const float*)d_in[4];
  float* out = (float*)d_out;
  char* ws = (char*)d_ws;

  u16* qkvB = (u16*)ws;                         // 192*65536*4 u16  = 100663296 B
  u16* wb = (u16*)(ws + 100663296);             // 768*256*2        = 393216 B
  float* bias8 = (float*)(ws + 101056512);      // 4*64*64*4        = 65536 B
  float* bias4 = (float*)(ws + 101122048);      // 4*16*16*4        = 4096 B

  k_prep<<<256, 256, 0, stream>>>(qkv_w, t0, t1, wb, bias4, bias8);
  k_gemm<<<2048, 512, 0, stream>>>(x, wb, qkv_b, qkvB);
  k_attn8<<<1024, 256, 0, stream>>>(qkvB, bias8, out);
  k_attn4<<<1024, 256, 0, stream>>>(qkvB, bias4, out);
}

// Round 12
// 107.739 us; speedup vs baseline: 5.5923x; 1.0990x over previous
//
#include <hip/hip_runtime.h>

typedef unsigned short u16;
typedef unsigned int u32;
typedef __attribute__((ext_vector_type(8))) short short8;   // 8 bf16 (MFMA A/B frag)
typedef __attribute__((ext_vector_type(4))) float f32x4;    // MFMA C/D frag
typedef __attribute__((ext_vector_type(4))) float fvec4;
typedef __attribute__((ext_vector_type(4))) u16 u16x4;

__device__ __forceinline__ u16 f2bf(float f) {
  u32 u = __float_as_uint(f);
  u += 0x7FFFu + ((u >> 16) & 1u);   // RTNE
  return (u16)(u >> 16);
}

// wave-local LDS fence: drains this wave's ds ops only (lgkmcnt), does NOT touch vmcnt
// so global prefetches stay in flight. sched_barrier pins ordering.
__device__ __forceinline__ void wave_lds_fence() {
  asm volatile("s_waitcnt lgkmcnt(0)" ::: "memory");
  __builtin_amdgcn_sched_barrier(0);
}

// memory row index of token (Bg,h,w); rows of x are 256 elems.
__device__ __forceinline__ int m_of(int Bg, int h, int w) {
  return ((Bg >> 2) << 14) | ((h & 3) << 12) | ((((Bg & 3) << 1) | (h >> 5)) << 9) |
         (((h >> 2) & 7) << 6) | w;
}

__device__ __forceinline__ f32x4 mfma16(short8 a, short8 b, f32x4 c) {
  return __builtin_amdgcn_mfma_f32_16x16x32_bf16(a, b, c, 0, 0, 0);
}

// qkvB blocked layout: element (channel c, token m) lives at (c>>2)*262144 + m*4 + (c&3).
__device__ __forceinline__ short8 ld8(const u16* __restrict__ qb, int c4, int m) {
  union { u16x4 h[2]; short8 v; } u;
  u.h[0] = *(const u16x4*)(qb + (size_t)c4 * 262144 + (size_t)m * 4);
  u.h[1] = *(const u16x4*)(qb + (size_t)(c4 + 1) * 262144 + (size_t)m * 4);
  return u.v;
}

// ---------------- prep: convert W to bf16, materialize bias matrices ----------------
__global__ void k_prep(const float* __restrict__ qkv_w, const float* __restrict__ t0,
                       const float* __restrict__ t1, u16* __restrict__ wb,
                       float* __restrict__ bias4, float* __restrict__ bias8) {
  int tid = blockIdx.x * 256 + threadIdx.x;
  int stride = gridDim.x * 256;
  for (int i = tid; i < 768 * 256; i += stride) wb[i] = f2bf(qkv_w[i]);
  for (int i = tid; i < 4 * 64 * 64; i += stride) {
    int g = i >> 12, n = (i >> 6) & 63, m = i & 63;
    int di = (n >> 3) - (m >> 3) + 7, dj = (n & 7) - (m & 7) + 7;
    bias8[i] = t1[(di * 15 + dj) * 4 + g];
  }
  for (int i = tid; i < 4 * 16 * 16; i += stride) {
    int g = i >> 8, n = (i >> 4) & 15, m = i & 15;
    int di = (n >> 2) - (m >> 2) + 3, dj = (n & 3) - (m & 3) + 3;
    bias4[i] = t0[(di * 7 + dj) * 4 + g];
  }
}

// ---------------- QKV GEMM: [65536 x 256] x [256 x 768] -> qkvB blocked layout ------------
// Grid 2048: bid>>10 = col-half (384 cols), bid&1023 = 64-row m-tile. 8 waves; wave owns
// 48 cols x 64 rows (acc 48 regs). As = 64x128 K-half (16KB, XOR slot-swizzle); Bs = per-
// wave 48-col K=32 slabs (24KB). Half1's x-loads pre-issued into regs right after the
// first barrier -> boundary exposes only cvt+ds_write. K-loop: read chunk -> write next
// chunk (DS in-order => WAR safe) -> prefetch chunk+2 -> MFMAs.
__global__ __launch_bounds__(512, 4) void k_gemm(const float* __restrict__ x,
                                                 const u16* __restrict__ wb,
                                                 const float* __restrict__ qkv_b,
                                                 u16* __restrict__ qkvB) {
  __shared__ __align__(16) u16 As[64 * 128];      // 16384 B, XOR slot-swizzled, K-half
  __shared__ __align__(16) u16 Bs[384 * 32];      // 24576 B, per-wave 48-col slabs
  const int t = threadIdx.x;
  const int wid = t >> 6, l = t & 63;
  const int lr = l & 15, lk4 = l >> 4;
  const int mt = blockIdx.x & 1023, nh = blockIdx.x >> 10;
  const size_t xbase = (size_t)mt * 64 * 256;
  const int colbase = nh * 384;            // this block's first output col

  // wave owns local cols wid*48 .. wid*48+47
  int goff[3], loff[3];
#pragma unroll
  for (int j = 0; j < 3; ++j) {
    int u = wid * 192 + j * 64 + l;        // unit = 8 u16 of one (col,slot)
    int cu = u >> 2, su = u & 3;
    goff[j] = (colbase + cu) * 256 + su * 8;                 // global (u16 units)
    loff[j] = cu * 32 + ((su ^ ((cu >> 1) & 3)) * 8);        // swizzled LDS addr
  }
  // A-stage unit mapping: 4 units/thread, unit = row x 8B-halfslot
  const int sr0 = t >> 5;                  // rows sr0, sr0+16, sr0+32, sr0+48
  const int scc = (t & 31) * 4;            // u16 col within 128-half
  const int sslot = scc >> 3, shalf = scc & 7;

  // ---- prologue: chunk0 loads, stage A half0, write Bs chunk0, load chunk1 ----
  short8 bstg[3];
#pragma unroll
  for (int j = 0; j < 3; ++j) bstg[j] = *(const short8*)(wb + goff[j]);
  {
    const float* xp = x + xbase + (size_t)sr0 * 256 + scc;
#pragma unroll
    for (int j = 0; j < 4; ++j) {
      fvec4 v = *(const fvec4*)(xp + j * 16 * 256);
      int r = sr0 + j * 16;
      u16x4 u;
      u[0] = f2bf(v[0]); u[1] = f2bf(v[1]); u[2] = f2bf(v[2]); u[3] = f2bf(v[3]);
      *(u16x4*)&As[r * 128 + ((sslot ^ (r & 7)) << 3) + shalf] = u;
    }
  }
#pragma unroll
  for (int j = 0; j < 3; ++j) *(short8*)&Bs[loff[j]] = bstg[j];   // chunk0 (vmcnt-waited)
#pragma unroll
  for (int j = 0; j < 3; ++j) bstg[j] = *(const short8*)(wb + goff[j] + 32);  // chunk1

  f32x4 acc[3][4];
  const f32x4 z = {0.f, 0.f, 0.f, 0.f};
#pragma unroll
  for (int jt = 0; jt < 3; ++jt)
#pragma unroll
    for (int rt = 0; rt < 4; ++rt) acc[jt][rt] = z;

  __syncthreads();  // As half0 + Bs chunk0 visible (drains chunk1 prefetch too)

  // pre-issue half1's x loads NOW: they land during half0's 4 chunks of compute
  fvec4 xv[4];
  {
    const float* xp = x + xbase + (size_t)sr0 * 256 + 128 + scc;
#pragma unroll
    for (int j = 0; j < 4; ++j) xv[j] = *(const fvec4*)(xp + j * 16 * 256);
  }

  const int bswz = (lr >> 1) & 3;          // B-read slot swizzle
#pragma unroll
  for (int ci = 0; ci < 8; ++ci) {
    if (ci == 4) {                         // K-half boundary: only cvt+write exposed
      __syncthreads();                     // all waves done reading As half0
#pragma unroll
      for (int j = 0; j < 4; ++j) {
        int r = sr0 + j * 16;
        u16x4 u;
        u[0] = f2bf(xv[j][0]); u[1] = f2bf(xv[j][1]);
        u[2] = f2bf(xv[j][2]); u[3] = f2bf(xv[j][3]);
        *(u16x4*)&As[r * 128 + ((sslot ^ (r & 7)) << 3) + shalf] = u;
      }
      __syncthreads();                     // As half1 visible
    }
    // reads of chunk ci; DS in-order per wave => safe to overwrite the slab after
    short8 a[4], b[3];
    const int kslot = (ci & 3) * 4 + lk4;
#pragma unroll
    for (int rt = 0; rt < 4; ++rt) {
      int row = rt * 16 + lr;
      a[rt] = *(const short8*)&As[row * 128 + ((kslot ^ (row & 7)) << 3)];
    }
#pragma unroll
    for (int jt = 0; jt < 3; ++jt)
      b[jt] = *(const short8*)&Bs[(wid * 48 + jt * 16 + lr) * 32 + ((lk4 ^ bswz) * 8)];
    __builtin_amdgcn_sched_barrier(0);     // keep the writes below AFTER the reads above
    // write chunk ci+1 (regs prefetched one iter ago; vmcnt wait ~free)
    if (ci < 7) {
#pragma unroll
      for (int j = 0; j < 3; ++j) *(short8*)&Bs[loff[j]] = bstg[j];
    }
    // prefetch chunk ci+2; stays in flight under the MFMAs
    if (ci < 6) {
#pragma unroll
      for (int j = 0; j < 3; ++j)
        bstg[j] = *(const short8*)(wb + goff[j] + (ci + 2) * 32);
    }
#pragma unroll
    for (int jt = 0; jt < 3; ++jt)
#pragma unroll
      for (int rt = 0; rt < 4; ++rt)
        acc[jt][rt] = mfma16(b[jt], a[rt], acc[jt][rt]);  // reg-dim = col
  }

  // ---- epilogue: + bias, blocked layout -> per-lane u16x4, coalesced ----
  const int rows0 = mt * 64;
#pragma unroll
  for (int jt = 0; jt < 3; ++jt) {
    int col0 = colbase + wid * 48 + jt * 16 + lk4 * 4;
    fvec4 bb = *(const fvec4*)(qkv_b + col0);
    int c40 = col0 >> 2;
#pragma unroll
    for (int rt = 0; rt < 4; ++rt) {
      int row = rows0 + rt * 16 + lr;
      u16x4 u;
#pragma unroll
      for (int r = 0; r < 4; ++r) u[r] = f2bf(acc[jt][rt][r] + bb[r]);
      *(u16x4*)&qkvB[(size_t)c40 * 262144 + (size_t)row * 4] = u;
    }
  }
}

// ---------------- attention ws=8 (group 1, channels 128..255) ----------------
// 1-wave blocks (grid 4096 = window x head), XCD-chunked swizzle so all windows of a
// spatial row share an XCD (store halves merge into full L2 lines). No barriers at all.
__global__ __launch_bounds__(64) void k_attn8(const u16* __restrict__ qkvB,
                                              const float* __restrict__ bias8,
                                              float* __restrict__ out) {
  __shared__ __align__(16) u16 vtg[32 * 72];  // V^T [e][m] (pad 8)
  __shared__ __align__(16) u16 plg[64 * 72];  // P [n][m]; reused as O f32 [64][33]
  const int lid = blockIdx.x;
  const int logical = (lid & 7) * 512 + (lid >> 3);  // bijective: 4096 = 8*512
  const int g = logical & 3;
  const int wj = (logical >> 2) & 7, wi = (logical >> 5) & 7, Bg = logical >> 8;
  const int h0 = wi * 8, w0 = wj * 8;
  const int l = threadIdx.x;
  const int lr = l & 15, lk4 = l >> 4;

  // load Q,K fragments straight from global (A-layout: row=l&15, k-chunk=(l>>4)*8)
  const int c4q = 32 + g * 8 + lk4 * 2;   // q chans 128+g*32+lk4*8
  const int c4k = 96 + g * 8 + lk4 * 2;   // k chans 384+g*32+lk4*8
  short8 aq[4], bk[4];
#pragma unroll
  for (int tn = 0; tn < 4; ++tn) {
    int n = tn * 16 + lr;
    int m = m_of(Bg, h0 + (n >> 3), w0 + (n & 7));
    aq[tn] = ld8(qkvB, c4q, m);
    bk[tn] = ld8(qkvB, c4k, m);
  }
  // stage V^T: lane l owns token m=l; v chans 640+g*32 .. +31 (8 c4-groups)
  {
    int m = m_of(Bg, h0 + (l >> 3), w0 + (l & 7));
#pragma unroll
    for (int j2 = 0; j2 < 8; ++j2) {
      u16x4 p = *(const u16x4*)(qkvB + (size_t)(160 + g * 8 + j2) * 262144 + (size_t)m * 4);
#pragma unroll
      for (int r = 0; r < 4; ++r) vtg[(j2 * 4 + r) * 72 + l] = p[r];
    }
  }
  // S = q k^T  (16 MFMAs)
  f32x4 z = {0.f, 0.f, 0.f, 0.f};
  f32x4 s[4][4];
#pragma unroll
  for (int tn = 0; tn < 4; ++tn)
#pragma unroll
    for (int tm = 0; tm < 4; ++tm) s[tn][tm] = mfma16(aq[tn], bk[tm], z);

  const float scale = 0.17677669529663687f;  // 1/sqrt(32)
#pragma unroll
  for (int tn = 0; tn < 4; ++tn)
#pragma unroll
    for (int tm = 0; tm < 4; ++tm)
#pragma unroll
      for (int r = 0; r < 4; ++r) {
        int n = tn * 16 + lk4 * 4 + r, m = tm * 16 + lr;
        s[tn][tm][r] = s[tn][tm][r] * scale + bias8[(g * 64 + n) * 64 + m];
      }
  // softmax over m (row n lives in 16 lanes sharing l>>4)
  float invden[4][4];
#pragma unroll
  for (int tn = 0; tn < 4; ++tn)
#pragma unroll
    for (int r = 0; r < 4; ++r) {
      float mx = fmaxf(fmaxf(s[tn][0][r], s[tn][1][r]), fmaxf(s[tn][2][r], s[tn][3][r]));
#pragma unroll
      for (int d = 1; d < 16; d <<= 1) mx = fmaxf(mx, __shfl_xor(mx, d));
      float sum = 0.f;
#pragma unroll
      for (int tm = 0; tm < 4; ++tm) {
        float p = __expf(s[tn][tm][r] - mx);
        s[tn][tm][r] = p;
        sum += p;
      }
#pragma unroll
      for (int d = 1; d < 16; d <<= 1) sum += __shfl_xor(sum, d);
      invden[tn][r] = 1.f / sum;
    }
  // P -> LDS (bf16)
#pragma unroll
  for (int tn = 0; tn < 4; ++tn)
#pragma unroll
    for (int tm = 0; tm < 4; ++tm)
#pragma unroll
      for (int r = 0; r < 4; ++r)
        plg[(tn * 16 + lk4 * 4 + r) * 72 + tm * 16 + lr] = f2bf(s[tn][tm][r]);
  wave_lds_fence();
  // O = P V  (16 MFMAs)
  f32x4 o[4][2];
#pragma unroll
  for (int tn = 0; tn < 4; ++tn) { o[tn][0] = z; o[tn][1] = z; }
#pragma unroll
  for (int kc = 0; kc < 2; ++kc) {
    short8 pa[4], vb[2];
#pragma unroll
    for (int tn = 0; tn < 4; ++tn)
      pa[tn] = *(const short8*)&plg[(tn * 16 + lr) * 72 + kc * 32 + lk4 * 8];
#pragma unroll
    for (int te = 0; te < 2; ++te)
      vb[te] = *(const short8*)&vtg[(te * 16 + lr) * 72 + kc * 32 + lk4 * 8];
#pragma unroll
    for (int tn = 0; tn < 4; ++tn)
#pragma unroll
      for (int te = 0; te < 2; ++te) o[tn][te] = mfma16(pa[tn], vb[te], o[tn][te]);
  }
  wave_lds_fence();
  // scale by 1/denom, transpose O through LDS (overlay on plg)
  float* ol = (float*)plg;  // [64][33]
#pragma unroll
  for (int tn = 0; tn < 4; ++tn)
#pragma unroll
    for (int te = 0; te < 2; ++te)
#pragma unroll
      for (int r = 0; r < 4; ++r) {
        int n = tn * 16 + lk4 * 4 + r;
        ol[n * 33 + te * 16 + lr] = o[tn][te][r] * invden[tn][r];
      }
  wave_lds_fence();
  // store: lane = token, loop e -> 32B-chunk runs along w (row-mates share XCD now)
  {
    int h = h0 + (l >> 3), w = w0 + (l & 7);
    size_t base = ((size_t)(Bg >> 2)) * 4194304 + (size_t)(((Bg & 3) * 2 + (h >> 5))) * 131072 +
                  (size_t)(((h >> 2) & 7)) * 16384 + (size_t)((h & 3) * 64 + w);
#pragma unroll
    for (int e = 0; e < 32; ++e) {
      int c = 128 + g * 32 + e;
      size_t idx = base + (size_t)(c >> 6) * 1048576 + (size_t)((c >> 3) & 7) * 2048 +
                   (size_t)(c & 7) * 256;
      out[idx] = ol[l * 33 + e];
    }
  }
}

// ---------------- attention ws=4 (group 0, channels 0..127) ----------------
// block = 4 windows (1024 blocks), wave = window, heads looped; per-wave buffers -> no barriers
__global__ __launch_bounds__(256) void k_attn4(const u16* __restrict__ qkvB,
                                               const float* __restrict__ bias4,
                                               float* __restrict__ out) {
  __shared__ __align__(16) u16 vt[4 * 32 * 40];   // per-wave V^T [e][m0..32] (m 16..31 zero)
  __shared__ __align__(16) u16 pl[4 * 16 * 40];   // per-wave P [n][m0..32] (m 16..31 zero)
  __shared__ __align__(16) float ol[4 * 16 * 33]; // per-wave O
  int wv = threadIdx.x >> 6, l = threadIdx.x & 63;
  int wid = blockIdx.x * 4 + wv;
  int Bg = wid >> 8, wi = (wid >> 4) & 15, wj = wid & 15;
  int h0 = wi * 4, w0 = wj * 4;
  int lr = l & 15, lk4 = l >> 4;
  u16* vtw = vt + wv * (32 * 40);
  u16* plw = pl + wv * (16 * 40);
  float* olw = ol + wv * (16 * 33);
  f32x4 z = {0.f, 0.f, 0.f, 0.f};
  short8 z8 = {0, 0, 0, 0, 0, 0, 0, 0};
  const float scale = 0.17677669529663687f;

  // per-lane token index
  int hq = h0 + (lr >> 2), wq = w0 + (lr & 3);
  const int mq = m_of(Bg, hq, wq);

  for (int g = 0; g < 4; ++g) {
    short8 aq = ld8(qkvB, g * 8 + lk4 * 2, mq);          // q chans g*32+lk4*8
    short8 bk = ld8(qkvB, 64 + g * 8 + lk4 * 2, mq);     // k chans 256+g*32+lk4*8
    // stage V^T: lane = (token lr) x (e-chunk lk4)
    {
      short8 v = ld8(qkvB, 128 + g * 8 + lk4 * 2, mq);   // v chans 512+g*32+lk4*8
#pragma unroll
      for (int j = 0; j < 8; ++j) vtw[(lk4 * 8 + j) * 40 + lr] = (u16)v[j];
      // zero pad m in [16,32)
      *(short8*)&vtw[(l >> 1) * 40 + 16 + (l & 1) * 8] = z8;
    }
    // S (1 MFMA), C rows n = lk4*4+r, cols m = lr
    f32x4 s = mfma16(aq, bk, z);
#pragma unroll
    for (int r = 0; r < 4; ++r) {
      int n = lk4 * 4 + r;
      s[r] = s[r] * scale + bias4[(g * 16 + n) * 16 + lr];
    }
    float invden[4];
#pragma unroll
    for (int r = 0; r < 4; ++r) {
      float mx = s[r];
#pragma unroll
      for (int d = 1; d < 16; d <<= 1) mx = fmaxf(mx, __shfl_xor(mx, d));
      float p = __expf(s[r] - mx);
      s[r] = p;
      float sum = p;
#pragma unroll
      for (int d = 1; d < 16; d <<= 1) sum += __shfl_xor(sum, d);
      invden[r] = 1.f / sum;
    }
    // P -> LDS + zero pad
#pragma unroll
    for (int r = 0; r < 4; ++r) plw[(lk4 * 4 + r) * 40 + lr] = f2bf(s[r]);
    *(u16x4*)&plw[lr * 40 + 16 + lk4 * 4] = (u16x4){0, 0, 0, 0};
    wave_lds_fence();
    // O = P V : 2 MFMAs (te halves), K zero-padded to 32
    f32x4 o[2];
#pragma unroll
    for (int te = 0; te < 2; ++te) {
      short8 pa = *(const short8*)&plw[lr * 40 + lk4 * 8];
      short8 vb = *(const short8*)&vtw[(te * 16 + lr) * 40 + lk4 * 8];
      o[te] = mfma16(pa, vb, z);
    }
#pragma unroll
    for (int te = 0; te < 2; ++te)
#pragma unroll
      for (int r = 0; r < 4; ++r) {
        int n = lk4 * 4 + r;
        olw[n * 33 + te * 16 + lr] = o[te][r] * invden[r];
      }
    wave_lds_fence();
    // store: lane = (token lr) x (e-chunk lk4)
    {
      int h = h0 + (lr >> 2), w = w0 + (lr & 3);
      size_t base = ((size_t)(Bg >> 2)) * 4194304 +
                    (size_t)(((Bg & 3) * 2 + (h >> 5))) * 131072 +
                    (size_t)(((h >> 2) & 7)) * 16384 + (size_t)((h & 3) * 64 + w);
#pragma unroll
      for (int ee = 0; ee < 8; ++ee) {
        int e = lk4 * 8 + ee;
        int c = g * 32 + e;
        size_t idx = base + (size_t)(c >> 6) * 1048576 + (size_t)((c >> 3) & 7) * 2048 +
                     (size_t)(c & 7) * 256;
        out[idx] = olw[lr * 33 + e];
      }
    }
    wave_lds_fence();  // protect per-wave buffer reuse across g iterations
  }
}

extern "C" void kernel_launch(void* const* d_in, const int* in_sizes, int n_in,
                              void* d_out, int out_size, void* d_ws, size_t ws_size,
                              hipStream_t stream) {
  const float* x = (const float*)d_in[0];
  const float* qkv_w = (const float*)d_in[1];
  const float* qkv_b = (const float*)d_in[2];
  const float* t0 = (const float*)d_in[3];
  const float* t1 = (const float*)d_in[4];
  float* out = (float*)d_out;
  char* ws = (char*)d_ws;

  u16* qkvB = (u16*)ws;                         // 192*65536*4 u16  = 100663296 B
  u16* wb = (u16*)(ws + 100663296);             // 768*256*2        = 393216 B
  float* bias8 = (float*)(ws + 101056512);      // 4*64*64*4        = 65536 B
  float* bias4 = (float*)(ws + 101122048);      // 4*16*16*4        = 4096 B

  k_prep<<<256, 256, 0, stream>>>(qkv_w, t0, t1, wb, bias4, bias8);
  k_gemm<<<2048, 512, 0, stream>>>(x, wb, qkv_b, qkvB);
  k_attn8<<<4096, 64, 0, stream>>>(qkvB, bias8, out);
  k_attn4<<<1024, 256, 0, stream>>>(qkvB, bias4, out);
}

// Round 14
// 105.521 us; speedup vs baseline: 5.7099x; 1.0210x over previous
//
#include <hip/hip_runtime.h>

typedef unsigned short u16;
typedef unsigned int u32;
typedef __attribute__((ext_vector_type(8))) short short8;   // 8 bf16 (MFMA A/B frag)
typedef __attribute__((ext_vector_type(4))) float f32x4;    // MFMA C/D frag
typedef __attribute__((ext_vector_type(4))) float fvec4;
typedef __attribute__((ext_vector_type(4))) u16 u16x4;

typedef __attribute__((address_space(1))) void gvoid;
typedef __attribute__((address_space(3))) void lvoid;

__device__ __forceinline__ u16 f2bf(float f) {
  u32 u = __float_as_uint(f);
  u += 0x7FFFu + ((u >> 16) & 1u);   // RTNE
  return (u16)(u >> 16);
}

// async global->LDS DMA, 16B/lane: LDS dest = uniform base + lane*16, global src per-lane.
__device__ __forceinline__ void gl16(const u16* g, u16* d) {
  __builtin_amdgcn_global_load_lds((gvoid*)g, (lvoid*)d, 16, 0, 0);
}

// wave-local LDS fence: drains this wave's ds ops only (lgkmcnt), does NOT touch vmcnt.
__device__ __forceinline__ void wave_lds_fence() {
  asm volatile("s_waitcnt lgkmcnt(0)" ::: "memory");
  __builtin_amdgcn_sched_barrier(0);
}

// memory row index of token (Bg,h,w); rows of x are 256 elems.
__device__ __forceinline__ int m_of(int Bg, int h, int w) {
  return ((Bg >> 2) << 14) | ((h & 3) << 12) | ((((Bg & 3) << 1) | (h >> 5)) << 9) |
         (((h >> 2) & 7) << 6) | w;
}

__device__ __forceinline__ f32x4 mfma16(short8 a, short8 b, f32x4 c) {
  return __builtin_amdgcn_mfma_f32_16x16x32_bf16(a, b, c, 0, 0, 0);
}

// qkvB blocked layout: element (channel c, token m) lives at (c>>2)*262144 + m*4 + (c&3).
__device__ __forceinline__ short8 ld8(const u16* __restrict__ qb, int c4, int m) {
  union { u16x4 h[2]; short8 v; } u;
  u.h[0] = *(const u16x4*)(qb + (size_t)c4 * 262144 + (size_t)m * 4);
  u.h[1] = *(const u16x4*)(qb + (size_t)(c4 + 1) * 262144 + (size_t)m * 4);
  return u.v;
}

// ---------------- prep: pack W into DMA-ready swizzled order + bias matrices --------------
// wbp layout: [(nh*8+chunk)*1536 + p]*8+e  where unit p holds col cu=(p>>2) and k-slot
// su=(p&3)^((cu>>1)&3): linear DMA order lands exactly in the swizzled LDS layout reads expect.
__global__ void k_prep(const float* __restrict__ qkv_w, const float* __restrict__ t0,
                       const float* __restrict__ t1, u16* __restrict__ wbp,
                       float* __restrict__ bias4, float* __restrict__ bias8) {
  int tid = blockIdx.x * 256 + threadIdx.x;
  int stride = gridDim.x * 256;
  for (int i = tid; i < 196608; i += stride) {
    int nhc = i / 12288;              // (nh*8 + chunk) in [0,16)
    int rem = i - nhc * 12288;
    int p = rem >> 3, e = rem & 7;
    int cu = p >> 2;
    int su = (p & 3) ^ ((cu >> 1) & 3);
    int col = (nhc >> 3) * 384 + cu;
    int k = (nhc & 7) * 32 + su * 8 + e;
    wbp[i] = f2bf(qkv_w[col * 256 + k]);
  }
  for (int i = tid; i < 4 * 64 * 64; i += stride) {
    int g = i >> 12, n = (i >> 6) & 63, m = i & 63;
    int di = (n >> 3) - (m >> 3) + 7, dj = (n & 7) - (m & 7) + 7;
    bias8[i] = t1[(di * 15 + dj) * 4 + g];
  }
  for (int i = tid; i < 4 * 16 * 16; i += stride) {
    int g = i >> 8, n = (i >> 4) & 15, m = i & 15;
    int di = (n >> 2) - (m >> 2) + 3, dj = (n & 3) - (m & 3) + 3;
    bias4[i] = t0[(di * 7 + dj) * 4 + g];
  }
}

// ---------------- QKV GEMM: [65536 x 256] x [256 x 768] -> qkvB blocked layout ------------
// Grid 2048: bid>>10 = col-half (384 cols), bid&1023 = 64-row m-tile. 8 waves; wave owns
// 48 cols x 64 rows. B staged via global_load_lds DMA (pre-swizzled wbp) into PER-WAVE
// double-buffered 3KB slabs. ROUND-14 FIX: full vmcnt(0) drain at iteration top BEFORE
// issuing next chunk's DMAs (1-deep pipeline) — immune to compiler-scheduled stray VMEM
// that corrupted round-13's hand-counted vmcnt(3). Raw s_barrier only at K-half restage.
__global__ __launch_bounds__(512, 4) void k_gemm(const float* __restrict__ x,
                                                 const u16* __restrict__ wbp,
                                                 const float* __restrict__ qkv_b,
                                                 u16* __restrict__ qkvB) {
  __shared__ __align__(16) u16 As[64 * 128];       // 16384 B, XOR slot-swizzled, K-half
  __shared__ __align__(16) u16 Bs[2 * 8 * 1536];   // 49152 B: [buf][wave][48 cols x 32 k]
  const int t = threadIdx.x;
  const int wid = t >> 6, l = t & 63;
  const int lr = l & 15, lk4 = l >> 4;
  const int mt = blockIdx.x & 1023, nh = blockIdx.x >> 10;
  const size_t xbase = (size_t)mt * 64 * 256;
  const int colbase = nh * 384;            // this block's first output col

  // B DMA geometry: src has per-lane l*8; dest base is wave-uniform (HW adds lane*16B)
  const u16* wsrc = wbp + (size_t)(nh * 8) * 12288 + (wid * 192 + l) * 8;
  u16* bdst = &Bs[wid * 1536];

  // A-stage unit mapping: 4 units/thread
  const int sr0 = t >> 5;                  // rows sr0, sr0+16, sr0+32, sr0+48
  const int scc = (t & 31) * 4;            // u16 col within 128-half
  const int sslot = scc >> 3, shalf = scc & 7;

  // ---- prologue ----
  // half1 x loads first (consumed at the K-half boundary)
  fvec4 xv[4];
  {
    const float* xp1 = x + xbase + (size_t)sr0 * 256 + 128 + scc;
#pragma unroll
    for (int j = 0; j < 4; ++j) xv[j] = *(const fvec4*)(xp1 + j * 16 * 256);
  }
  // DMA chunk 0 -> buf0
#pragma unroll
  for (int j = 0; j < 3; ++j) gl16(wsrc + j * 512, bdst + j * 512);
  // stage A half0 (f32 loads -> cvt -> ds_write)
  {
    const float* xp = x + xbase + (size_t)sr0 * 256 + scc;
#pragma unroll
    for (int j = 0; j < 4; ++j) {
      fvec4 v = *(const fvec4*)(xp + j * 16 * 256);
      int r = sr0 + j * 16;
      u16x4 u;
      u[0] = f2bf(v[0]); u[1] = f2bf(v[1]); u[2] = f2bf(v[2]); u[3] = f2bf(v[3]);
      *(u16x4*)&As[r * 128 + ((sslot ^ (r & 7)) << 3) + shalf] = u;
    }
  }
  asm volatile("s_waitcnt lgkmcnt(0)" ::: "memory");
  __builtin_amdgcn_s_barrier();            // As half0 visible (DMAs may stay in flight)

  f32x4 acc[3][4];
  const f32x4 z = {0.f, 0.f, 0.f, 0.f};
#pragma unroll
  for (int jt = 0; jt < 3; ++jt)
#pragma unroll
    for (int rt = 0; rt < 4; ++rt) acc[jt][rt] = z;

  const int bswz = (lr >> 1) & 3;          // B-read slot swizzle
#pragma unroll
  for (int ci = 0; ci < 8; ++ci) {
    if (ci == 4) {                         // K-half boundary: restage As from regs
      __builtin_amdgcn_s_barrier();        // all half0 reads retired (reg-consumed)
#pragma unroll
      for (int j = 0; j < 4; ++j) {
        int r = sr0 + j * 16;
        u16x4 u;
        u[0] = f2bf(xv[j][0]); u[1] = f2bf(xv[j][1]);
        u[2] = f2bf(xv[j][2]); u[3] = f2bf(xv[j][3]);
        *(u16x4*)&As[r * 128 + ((sslot ^ (r & 7)) << 3) + shalf] = u;
      }
      asm volatile("s_waitcnt lgkmcnt(0)" ::: "memory");
      __builtin_amdgcn_s_barrier();        // As half1 visible
    }
    const int buf = ci & 1;
    // FULL drain: chunk ci (issued one iter ago, or prologue) has landed. Any
    // compiler-scheduled stray loads are drained too -> no count confusion.
    asm volatile("s_waitcnt vmcnt(0)" ::: "memory");
    __builtin_amdgcn_sched_barrier(0);
    // issue DMA for chunk ci+1 into the other buffer; lands during the MFMAs below
    if (ci < 7) {
      const u16* s = wsrc + (size_t)(ci + 1) * 12288;
      u16* d = bdst + (buf ^ 1) * 12288;
#pragma unroll
      for (int j = 0; j < 3; ++j) gl16(s + j * 512, d + j * 512);
    }
    // reads (LDS only)
    short8 a[4], b[3];
    const int kslot = (ci & 3) * 4 + lk4;
#pragma unroll
    for (int rt = 0; rt < 4; ++rt) {
      int row = rt * 16 + lr;
      a[rt] = *(const short8*)&As[row * 128 + ((kslot ^ (row & 7)) << 3)];
    }
#pragma unroll
    for (int jt = 0; jt < 3; ++jt)
      b[jt] = *(const short8*)&Bs[buf * 12288 + wid * 1536 +
                                  (jt * 16 + lr) * 32 + ((lk4 ^ bswz) * 8)];
#pragma unroll
    for (int jt = 0; jt < 3; ++jt)
#pragma unroll
      for (int rt = 0; rt < 4; ++rt)
        acc[jt][rt] = mfma16(b[jt], a[rt], acc[jt][rt]);  // reg-dim = col
  }

  // ---- epilogue: + bias, blocked layout -> per-lane u16x4, coalesced ----
  const int rows0 = mt * 64;
#pragma unroll
  for (int jt = 0; jt < 3; ++jt) {
    int col0 = colbase + wid * 48 + jt * 16 + lk4 * 4;
    fvec4 bb = *(const fvec4*)(qkv_b + col0);
    int c40 = col0 >> 2;
#pragma unroll
    for (int rt = 0; rt < 4; ++rt) {
      int row = rows0 + rt * 16 + lr;
      u16x4 u;
#pragma unroll
      for (int r = 0; r < 4; ++r) u[r] = f2bf(acc[jt][rt][r] + bb[r]);
      *(u16x4*)&qkvB[(size_t)c40 * 262144 + (size_t)row * 4] = u;
    }
  }
}

// ---------------- attention ws=8 (group 1, channels 128..255) ----------------
// 1-wave blocks (grid 4096 = window x head), XCD-chunked swizzle; no barriers at all.
__global__ __launch_bounds__(64) void k_attn8(const u16* __restrict__ qkvB,
                                              const float* __restrict__ bias8,
                                              float* __restrict__ out) {
  __shared__ __align__(16) u16 vtg[32 * 72];  // V^T [e][m] (pad 8)
  __shared__ __align__(16) u16 plg[64 * 72];  // P [n][m]; reused as O f32 [64][33]
  const int lid = blockIdx.x;
  const int logical = (lid & 7) * 512 + (lid >> 3);  // bijective: 4096 = 8*512
  const int g = logical & 3;
  const int wj = (logical >> 2) & 7, wi = (logical >> 5) & 7, Bg = logical >> 8;
  const int h0 = wi * 8, w0 = wj * 8;
  const int l = threadIdx.x;
  const int lr = l & 15, lk4 = l >> 4;

  const int c4q = 32 + g * 8 + lk4 * 2;   // q chans 128+g*32+lk4*8
  const int c4k = 96 + g * 8 + lk4 * 2;   // k chans 384+g*32+lk4*8
  short8 aq[4], bk[4];
#pragma unroll
  for (int tn = 0; tn < 4; ++tn) {
    int n = tn * 16 + lr;
    int m = m_of(Bg, h0 + (n >> 3), w0 + (n & 7));
    aq[tn] = ld8(qkvB, c4q, m);
    bk[tn] = ld8(qkvB, c4k, m);
  }
  // stage V^T: lane l owns token m=l; v chans 640+g*32 .. +31 (8 c4-groups)
  {
    int m = m_of(Bg, h0 + (l >> 3), w0 + (l & 7));
#pragma unroll
    for (int j2 = 0; j2 < 8; ++j2) {
      u16x4 p = *(const u16x4*)(qkvB + (size_t)(160 + g * 8 + j2) * 262144 + (size_t)m * 4);
#pragma unroll
      for (int r = 0; r < 4; ++r) vtg[(j2 * 4 + r) * 72 + l] = p[r];
    }
  }
  // S = q k^T  (16 MFMAs)
  f32x4 z = {0.f, 0.f, 0.f, 0.f};
  f32x4 s[4][4];
#pragma unroll
  for (int tn = 0; tn < 4; ++tn)
#pragma unroll
    for (int tm = 0; tm < 4; ++tm) s[tn][tm] = mfma16(aq[tn], bk[tm], z);

  const float scale = 0.17677669529663687f;  // 1/sqrt(32)
#pragma unroll
  for (int tn = 0; tn < 4; ++tn)
#pragma unroll
    for (int tm = 0; tm < 4; ++tm)
#pragma unroll
      for (int r = 0; r < 4; ++r) {
        int n = tn * 16 + lk4 * 4 + r, m = tm * 16 + lr;
        s[tn][tm][r] = s[tn][tm][r] * scale + bias8[(g * 64 + n) * 64 + m];
      }
  // softmax over m (row n lives in 16 lanes sharing l>>4)
  float invden[4][4];
#pragma unroll
  for (int tn = 0; tn < 4; ++tn)
#pragma unroll
    for (int r = 0; r < 4; ++r) {
      float mx = fmaxf(fmaxf(s[tn][0][r], s[tn][1][r]), fmaxf(s[tn][2][r], s[tn][3][r]));
#pragma unroll
      for (int d = 1; d < 16; d <<= 1) mx = fmaxf(mx, __shfl_xor(mx, d));
      float sum = 0.f;
#pragma unroll
      for (int tm = 0; tm < 4; ++tm) {
        float p = __expf(s[tn][tm][r] - mx);
        s[tn][tm][r] = p;
        sum += p;
      }
#pragma unroll
      for (int d = 1; d < 16; d <<= 1) sum += __shfl_xor(sum, d);
      invden[tn][r] = 1.f / sum;
    }
  // P -> LDS (bf16)
#pragma unroll
  for (int tn = 0; tn < 4; ++tn)
#pragma unroll
    for (int tm = 0; tm < 4; ++tm)
#pragma unroll
      for (int r = 0; r < 4; ++r)
        plg[(tn * 16 + lk4 * 4 + r) * 72 + tm * 16 + lr] = f2bf(s[tn][tm][r]);
  wave_lds_fence();
  // O = P V  (16 MFMAs)
  f32x4 o[4][2];
#pragma unroll
  for (int tn = 0; tn < 4; ++tn) { o[tn][0] = z; o[tn][1] = z; }
#pragma unroll
  for (int kc = 0; kc < 2; ++kc) {
    short8 pa[4], vb[2];
#pragma unroll
    for (int tn = 0; tn < 4; ++tn)
      pa[tn] = *(const short8*)&plg[(tn * 16 + lr) * 72 + kc * 32 + lk4 * 8];
#pragma unroll
    for (int te = 0; te < 2; ++te)
      vb[te] = *(const short8*)&vtg[(te * 16 + lr) * 72 + kc * 32 + lk4 * 8];
#pragma unroll
    for (int tn = 0; tn < 4; ++tn)
#pragma unroll
      for (int te = 0; te < 2; ++te) o[tn][te] = mfma16(pa[tn], vb[te], o[tn][te]);
  }
  wave_lds_fence();
  // scale by 1/denom, transpose O through LDS (overlay on plg)
  float* ol = (float*)plg;  // [64][33]
#pragma unroll
  for (int tn = 0; tn < 4; ++tn)
#pragma unroll
    for (int te = 0; te < 2; ++te)
#pragma unroll
      for (int r = 0; r < 4; ++r) {
        int n = tn * 16 + lk4 * 4 + r;
        ol[n * 33 + te * 16 + lr] = o[tn][te][r] * invden[tn][r];
      }
  wave_lds_fence();
  // store: lane = token, loop e -> 32B-chunk runs along w (row-mates share XCD)
  {
    int h = h0 + (l >> 3), w = w0 + (l & 7);
    size_t base = ((size_t)(Bg >> 2)) * 4194304 + (size_t)(((Bg & 3) * 2 + (h >> 5))) * 131072 +
                  (size_t)(((h >> 2) & 7)) * 16384 + (size_t)((h & 3) * 64 + w);
#pragma unroll
    for (int e = 0; e < 32; ++e) {
      int c = 128 + g * 32 + e;
      size_t idx = base + (size_t)(c >> 6) * 1048576 + (size_t)((c >> 3) & 7) * 2048 +
                   (size_t)(c & 7) * 256;
      out[idx] = ol[l * 33 + e];
    }
  }
}

// ---------------- attention ws=4 (group 0, channels 0..127) ----------------
// block = 4 windows (1024 blocks), wave = window, heads looped; per-wave buffers -> no barriers
__global__ __launch_bounds__(256) void k_attn4(const u16* __restrict__ qkvB,
                                               const float* __restrict__ bias4,
                                               float* __restrict__ out) {
  __shared__ __align__(16) u16 vt[4 * 32 * 40];   // per-wave V^T [e][m0..32] (m 16..31 zero)
  __shared__ __align__(16) u16 pl[4 * 16 * 40];   // per-wave P [n][m0..32] (m 16..31 zero)
  __shared__ __align__(16) float ol[4 * 16 * 33]; // per-wave O
  int wv = threadIdx.x >> 6, l = threadIdx.x & 63;
  int wid = blockIdx.x * 4 + wv;
  int Bg = wid >> 8, wi = (wid >> 4) & 15, wj = wid & 15;
  int h0 = wi * 4, w0 = wj * 4;
  int lr = l & 15, lk4 = l >> 4;
  u16* vtw = vt + wv * (32 * 40);
  u16* plw = pl + wv * (16 * 40);
  float* olw = ol + wv * (16 * 33);
  f32x4 z = {0.f, 0.f, 0.f, 0.f};
  short8 z8 = {0, 0, 0, 0, 0, 0, 0, 0};
  const float scale = 0.17677669529663687f;

  // per-lane token index
  int hq = h0 + (lr >> 2), wq = w0 + (lr & 3);
  const int mq = m_of(Bg, hq, wq);

  for (int g = 0; g < 4; ++g) {
    short8 aq = ld8(qkvB, g * 8 + lk4 * 2, mq);          // q chans g*32+lk4*8
    short8 bk = ld8(qkvB, 64 + g * 8 + lk4 * 2, mq);     // k chans 256+g*32+lk4*8
    // stage V^T: lane = (token lr) x (e-chunk lk4)
    {
      short8 v = ld8(qkvB, 128 + g * 8 + lk4 * 2, mq);   // v chans 512+g*32+lk4*8
#pragma unroll
      for (int j = 0; j < 8; ++j) vtw[(lk4 * 8 + j) * 40 + lr] = (u16)v[j];
      // zero pad m in [16,32)
      *(short8*)&vtw[(l >> 1) * 40 + 16 + (l & 1) * 8] = z8;
    }
    // S (1 MFMA), C rows n = lk4*4+r, cols m = lr
    f32x4 s = mfma16(aq, bk, z);
#pragma unroll
    for (int r = 0; r < 4; ++r) {
      int n = lk4 * 4 + r;
      s[r] = s[r] * scale + bias4[(g * 16 + n) * 16 + lr];
    }
    float invden[4];
#pragma unroll
    for (int r = 0; r < 4; ++r) {
      float mx = s[r];
#pragma unroll
      for (int d = 1; d < 16; d <<= 1) mx = fmaxf(mx, __shfl_xor(mx, d));
      float p = __expf(s[r] - mx);
      s[r] = p;
      float sum = p;
#pragma unroll
      for (int d = 1; d < 16; d <<= 1) sum += __shfl_xor(sum, d);
      invden[r] = 1.f / sum;
    }
    // P -> LDS + zero pad
#pragma unroll
    for (int r = 0; r < 4; ++r) plw[(lk4 * 4 + r) * 40 + lr] = f2bf(s[r]);
    *(u16x4*)&plw[lr * 40 + 16 + lk4 * 4] = (u16x4){0, 0, 0, 0};
    wave_lds_fence();
    // O = P V : 2 MFMAs (te halves), K zero-padded to 32
    f32x4 o[2];
#pragma unroll
    for (int te = 0; te < 2; ++te) {
      short8 pa = *(const short8*)&plw[lr * 40 + lk4 * 8];
      short8 vb = *(const short8*)&vtw[(te * 16 + lr) * 40 + lk4 * 8];
      o[te] = mfma16(pa, vb, z);
    }
#pragma unroll
    for (int te = 0; te < 2; ++te)
#pragma unroll
      for (int r = 0; r < 4; ++r) {
        int n = lk4 * 4 + r;
        olw[n * 33 + te * 16 + lr] = o[te][r] * invden[r];
      }
    wave_lds_fence();
    // store: lane = (token lr) x (e-chunk lk4)
    {
      int h = h0 + (lr >> 2), w = w0 + (lr & 3);
      size_t base = ((size_t)(Bg >> 2)) * 4194304 +
                    (size_t)(((Bg & 3) * 2 + (h >> 5))) * 131072 +
                    (size_t)(((h >> 2) & 7)) * 16384 + (size_t)((h & 3) * 64 + w);
#pragma unroll
      for (int ee = 0; ee < 8; ++ee) {
        int e = lk4 * 8 + ee;
        int c = g * 32 + e;
        size_t idx = base + (size_t)(c >> 6) * 1048576 + (size_t)((c >> 3) & 7) * 2048 +
                     (size_t)(c & 7) * 256;
        out[idx] = olw[lr * 33 + e];
      }
    }
    wave_lds_fence();  // protect per-wave buffer reuse across g iterations
  }
}

extern "C" void kernel_launch(void* const* d_in, const int* in_sizes, int n_in,
                              void* d_out, int out_size, void* d_ws, size_t ws_size,
                              hipStream_t stream) {
  const float* x = (const float*)d_in[0];
  const float* qkv_w = (const float*)d_in[1];
  const float* qkv_b = (const float*)d_in[2];
  const float* t0 = (const float*)d_in[3];
  const float* t1 = (const float*)d_in[4];
  float* out = (float*)d_out;
  char* ws = (char*)d_ws;

  u16* qkvB = (u16*)ws;                         // 192*65536*4 u16  = 100663296 B
  u16* wbp = (u16*)(ws + 100663296);            // 196608 u16       = 393216 B
  float* bias8 = (float*)(ws + 101056512);      // 4*64*64*4        = 65536 B
  float* bias4 = (float*)(ws + 101122048);      // 4*16*16*4        = 4096 B

  k_prep<<<256, 256, 0, stream>>>(qkv_w, t0, t1, wbp, bias4, bias8);
  k_gemm<<<2048, 512, 0, stream>>>(x, wbp, qkv_b, qkvB);
  k_attn8<<<4096, 64, 0, stream>>>(qkvB, bias8, out);
  k_attn4<<<1024, 256, 0, stream>>>(qkvB, bias4, out);
}